// Round 3
// baseline (257.649 us; speedup 1.0000x reference)
//
#include <hip/hip_runtime.h>

// SelfAttention (lambda attention) on MI355X.
// B=8, C=256, H=W=32, n=1024, DK=64, HEADS=4, DQ=256, DV=64. SF = 64^-0.25
#define SFC 0.35355339059327373f

typedef __attribute__((ext_vector_type(8))) short short8;
typedef __attribute__((ext_vector_type(16))) float f32x16;
typedef unsigned short ushort_t;

__device__ __forceinline__ float4 ld4(const float* p) { return *reinterpret_cast<const float4*>(p); }
__device__ __forceinline__ void st4(float* p, float4 v) { *reinterpret_cast<float4*>(p) = v; }

union F4 { float4 v; float f[4]; };
union S8 { short8 v; ushort_t u[8]; };

__device__ __forceinline__ ushort_t bfb(float f) {
  union { float f; unsigned u; } a; a.f = f;
  unsigned r = a.u + 0x7FFFu + ((a.u >> 16) & 1u);   // RNE f32->bf16
  return (ushort_t)(r >> 16);
}

__device__ __forceinline__ void gl16(const void* g, void* l) {
  __builtin_amdgcn_global_load_lds(
      (const __attribute__((address_space(1))) unsigned int*)g,
      (__attribute__((address_space(3))) unsigned int*)l, 16, 0, 0);
}

// ---------------------------------------------------------------------------
// K0: prep. blocks 0..62: rpe -> RPEB bf16 [di][64 rows dj][72] (9216B slices)
//           blocks 63..110: Wq/Wk/Wv -> WB bf16 [384][256]
//           blocks 111..1134: x -> XBT bf16 [b*1024+n][256 c]
// ---------------------------------------------------------------------------
__global__ __launch_bounds__(256) void k_prep(
    const float* __restrict__ rpe, const float* __restrict__ wq,
    const float* __restrict__ wk, const float* __restrict__ wv,
    const float* __restrict__ x, ushort_t* __restrict__ RPEB,
    ushort_t* __restrict__ WB, ushort_t* __restrict__ XBT)
{
  const int bx = blockIdx.x, t = threadIdx.x;
  if (bx < 63) {
    const int di = bx;
#pragma unroll
    for (int i = 0; i < 2; ++i) {
      const int c = t + i * 256;
      if (c < 504) {
        const int dj = c >> 3, k8 = (c & 7) * 8;
        const float* s = rpe + (size_t)di * 4032 + dj * 64 + k8;
        float4 a = ld4(s), b = ld4(s + 4);
        S8 o;
        o.u[0] = bfb(a.x); o.u[1] = bfb(a.y); o.u[2] = bfb(a.z); o.u[3] = bfb(a.w);
        o.u[4] = bfb(b.x); o.u[5] = bfb(b.y); o.u[6] = bfb(b.z); o.u[7] = bfb(b.w);
        *(short8*)(RPEB + (size_t)di * 4608 + dj * 72 + k8) = o.v;
      }
    }
  } else if (bx < 111) {
    const int cc = (bx - 63) * 256 + t;        // 0..12287
    const int o = cc >> 5, k8 = (cc & 31) * 8;
    const float* src = (o < 256) ? (wq + o * 256)
                      : (o < 320) ? (wk + (o - 256) * 256)
                                  : (wv + (o - 320) * 256);
    float4 a = ld4(src + k8), b = ld4(src + k8 + 4);
    S8 s;
    s.u[0] = bfb(a.x); s.u[1] = bfb(a.y); s.u[2] = bfb(a.z); s.u[3] = bfb(a.w);
    s.u[4] = bfb(b.x); s.u[5] = bfb(b.y); s.u[6] = bfb(b.z); s.u[7] = bfb(b.w);
    *(short8*)(WB + (size_t)o * 256 + k8) = s.v;
  } else {
    const int id = (bx - 111) * 256 + t;       // 0..262143
    const int ng = id & 8191, c8 = id >> 13;   // n global, c chunk
    const int bb = ng >> 10, nn = ng & 1023;
    const float* src = x + (size_t)bb * 262144 + (size_t)(c8 * 8) * 1024 + nn;
    S8 s;
#pragma unroll
    for (int j = 0; j < 8; ++j) s.u[j] = bfb(src[(size_t)j * 1024]);
    *(short8*)(XBT + (size_t)ng * 256 + c8 * 8) = s.v;
  }
}

// ---------------------------------------------------------------------------
// K1: projection GEMM via MFMA: P[o][col] = sum_c WB[o][c] * XBT[col][c].
// BM=64, BN=128, K=256 (BK=64). 4 waves (2m x 2n). Blocks with bm==5 (V rows)
// also emit VB bf16 slices [b][i2][v][40].
// ---------------------------------------------------------------------------
__global__ __launch_bounds__(256) void k_projm(
    const ushort_t* __restrict__ WB, const ushort_t* __restrict__ XBT,
    float* __restrict__ P, ushort_t* __restrict__ VB)
{
  __shared__ ushort_t At[64 * 72];    // 9216 B
  __shared__ ushort_t Bt[128 * 72];   // 18432 B
  const int t = threadIdx.x;
  const int bm = blockIdx.x, bn = blockIdx.y;
  const int o0 = bm * 64, col0 = bn * 128;
  const int w = t >> 6, l = t & 63, ln = l & 31, hi = l >> 5;
  const int wm = w & 1, wn = w >> 1;

  f32x16 acc0, acc1;
#pragma unroll
  for (int i = 0; i < 16; ++i) { acc0[i] = 0.f; acc1[i] = 0.f; }

  for (int k0 = 0; k0 < 256; k0 += 64) {
    __syncthreads();
#pragma unroll
    for (int i = 0; i < 2; ++i) {
      const int c = t + i * 256, row = c >> 3, k8 = (c & 7) * 8;
      *(short8*)(At + row * 72 + k8) =
          *(const short8*)(WB + (size_t)(o0 + row) * 256 + k0 + k8);
    }
#pragma unroll
    for (int i = 0; i < 4; ++i) {
      const int c = t + i * 256, row = c >> 3, k8 = (c & 7) * 8;
      *(short8*)(Bt + row * 72 + k8) =
          *(const short8*)(XBT + (size_t)(col0 + row) * 256 + k0 + k8);
    }
    __syncthreads();
    const ushort_t* ka  = At + (wm * 32 + ln) * 72 + hi * 8;
    const ushort_t* kb0 = Bt + (wn * 64 + ln) * 72 + hi * 8;
    const ushort_t* kb1 = Bt + (wn * 64 + 32 + ln) * 72 + hi * 8;
#pragma unroll
    for (int kc = 0; kc < 4; ++kc) {
      short8 a = *(const short8*)(ka + kc * 16);
      acc0 = __builtin_amdgcn_mfma_f32_32x32x16_bf16(a, *(const short8*)(kb0 + kc * 16), acc0, 0, 0, 0);
      acc1 = __builtin_amdgcn_mfma_f32_32x32x16_bf16(a, *(const short8*)(kb1 + kc * 16), acc1, 0, 0, 0);
    }
  }

  // write P (f32)
#pragma unroll
  for (int r = 0; r < 16; ++r) {
    const int o = o0 + wm * 32 + (r & 3) + 8 * (r >> 2) + 4 * hi;
    float* dst = P + (size_t)o * 8192 + col0 + wn * 64 + ln;
    dst[0]  = acc0[r];
    dst[32] = acc1[r];
  }
  // V-rows also emit bf16 VB slices
  if (bm == 5) {
    const int b2 = bn >> 3;
#pragma unroll
    for (int r = 0; r < 16; ++r) {
      const int v = wm * 32 + (r & 3) + 8 * (r >> 2) + 4 * hi;
      const int i20 = (bn & 7) * 4 + wn * 2;
      VB[(size_t)(b2 * 32 + i20) * 2560 + v * 40 + ln]     = bfb(acc0[r]);
      VB[(size_t)(b2 * 32 + i20 + 1) * 2560 + v * 40 + ln] = bfb(acc1[r]);
    }
  }
}

// ---------------------------------------------------------------------------
// K2: BN stats per channel, folded with gamma/beta and SF.
// ---------------------------------------------------------------------------
__global__ __launch_bounds__(256) void k_stats(
    const float* __restrict__ P, const float* __restrict__ gq,
    const float* __restrict__ bq, const float* __restrict__ gk,
    const float* __restrict__ bk, float* __restrict__ scale,
    float* __restrict__ shift)
{
  const int ch = blockIdx.x;  // 0..319
  const float4* row = (const float4*)(P + (size_t)ch * 8192);
  float s = 0.f, ss = 0.f;
  for (int i = threadIdx.x; i < 2048; i += 256) {
    float4 v = row[i];
    s  += v.x + v.y + v.z + v.w;
    ss += v.x * v.x + v.y * v.y + v.z * v.z + v.w * v.w;
  }
#pragma unroll
  for (int off = 32; off; off >>= 1) {
    s  += __shfl_down(s, off, 64);
    ss += __shfl_down(ss, off, 64);
  }
  __shared__ float red[8];
  const int w = threadIdx.x >> 6, lane = threadIdx.x & 63;
  if (lane == 0) { red[w] = s; red[4 + w] = ss; }
  __syncthreads();
  if (threadIdx.x == 0) {
    s = red[0] + red[1] + red[2] + red[3];
    ss = red[4] + red[5] + red[6] + red[7];
    const float mu = s * (1.0f / 8192.0f);
    const float var = ss * (1.0f / 8192.0f) - mu * mu;
    const float rsig = rsqrtf(var + 1e-5f);
    float g, be;
    if (ch < 256) { g = gq[ch]; be = bq[ch]; }
    else          { g = gk[ch - 256]; be = bk[ch - 256]; }
    const float sc = rsig * g * SFC;
    scale[ch] = sc;
    shift[ch] = be * SFC - mu * sc;
  }
}

// ---------------------------------------------------------------------------
// K3: softmax over n for each (b, k-channel).
// ---------------------------------------------------------------------------
__global__ __launch_bounds__(256) void k_softmax(
    const float* __restrict__ P, const float* __restrict__ scale,
    const float* __restrict__ shift, float* __restrict__ KS)
{
  const int b = blockIdx.x >> 6, kc = blockIdx.x & 63;
  const int ch = 256 + kc;
  const float4* row = (const float4*)(P + (size_t)ch * 8192 + b * 1024);
  const float sc = scale[ch], sh = shift[ch];
  float4 v = row[threadIdx.x];
  float y0 = v.x * sc + sh, y1 = v.y * sc + sh;
  float y2 = v.z * sc + sh, y3 = v.w * sc + sh;
  float m = fmaxf(fmaxf(y0, y1), fmaxf(y2, y3));
#pragma unroll
  for (int off = 32; off; off >>= 1) m = fmaxf(m, __shfl_xor(m, off, 64));
  __shared__ float red[8];
  const int w = threadIdx.x >> 6, lane = threadIdx.x & 63;
  if (lane == 0) red[w] = m;
  __syncthreads();
  m = fmaxf(fmaxf(red[0], red[1]), fmaxf(red[2], red[3]));
  const float e0 = __expf(y0 - m), e1 = __expf(y1 - m);
  const float e2 = __expf(y2 - m), e3 = __expf(y3 - m);
  float su = e0 + e1 + e2 + e3;
#pragma unroll
  for (int off = 32; off; off >>= 1) su += __shfl_xor(su, off, 64);
  if (lane == 0) red[4 + w] = su;
  __syncthreads();
  const float inv = 1.0f / (red[4] + red[5] + red[6] + red[7]);
  ((float4*)(KS + (size_t)(b * 64 + kc) * 1024))[threadIdx.x] =
      make_float4(e0 * inv, e1 * inv, e2 * inv, e3 * inv);
}

// ---------------------------------------------------------------------------
// K4: content context partials: ctxp[b][nc][kc][vc] = sum_{n in chunk} ks*v
// ---------------------------------------------------------------------------
__global__ __launch_bounds__(256) void k_ctx(
    const float* __restrict__ KS, const float* __restrict__ P,
    float* __restrict__ ctxp)
{
  __shared__ float ksl[64][64];
  __shared__ float vl[64][64];
  const int t = threadIdx.x;
  const int b = blockIdx.x;
  const int n0 = blockIdx.y * 64;
  {
    const int c = t >> 2, q4 = (t & 3) * 16;
    const float* s = KS + (size_t)(b * 64 + c) * 1024 + n0 + q4;
#pragma unroll
    for (int i = 0; i < 16; ++i) ksl[q4 + i][c] = s[i];
    const float* v = P + (size_t)(320 + c) * 8192 + b * 1024 + n0 + q4;
#pragma unroll
    for (int i = 0; i < 16; ++i) vl[q4 + i][c] = v[i];
  }
  __syncthreads();
  const int tr = t >> 4, tc = t & 15;
  float acc[4][4] = {};
#pragma unroll 4
  for (int nn = 0; nn < 64; ++nn) {
    F4 a; a.v = ld4(&ksl[nn][tr * 4]);
    F4 bv; bv.v = ld4(&vl[nn][tc * 4]);
#pragma unroll
    for (int i = 0; i < 4; ++i)
#pragma unroll
      for (int j = 0; j < 4; ++j) acc[i][j] += a.f[i] * bv.f[j];
  }
  float* dst = ctxp + (size_t)(b * 16 + blockIdx.y) * 4096;
#pragma unroll
  for (int i = 0; i < 4; ++i)
    st4(dst + (tr * 4 + i) * 64 + tc * 4,
        make_float4(acc[i][0], acc[i][1], acc[i][2], acc[i][3]));
}

// reduce partials -> CTXB bf16 [b][v=64][72 k-pad] (9216B per b)
__global__ __launch_bounds__(256) void k_ctxred(
    const float* __restrict__ ctxp, ushort_t* __restrict__ ctxb)
{
  const int i = blockIdx.x * 256 + threadIdx.x;  // 32768
  const int b = i >> 12, r = i & 4095, kc = r >> 6, vc = r & 63;
  float s = 0.f;
#pragma unroll
  for (int c = 0; c < 16; ++c) s += ctxp[(size_t)(b * 16 + c) * 4096 + r];
  ctxb[(size_t)b * 4608 + vc * 72 + kc] = bfb(s);
}

// ---------------------------------------------------------------------------
// K5: positional lambda via MFMA, block = (b, i1, half). 8 waves: m=w&3, nt=w>>2.
// Staging: global_load_lds of prep'd bf16 slices (RPEB 9216B + VB 5120B),
// double-buffered. Per i2: T-GEMM (4 MFMA), shear -> Sl, SV (2 MFMA).
// Half 0 adds content GEMM from CTXB. Output combined via atomicAdd.
// ---------------------------------------------------------------------------
extern __shared__ char ldsc[];

__global__ __launch_bounds__(512) void k_pos(
    const float* __restrict__ P, const ushort_t* __restrict__ RPEB,
    const ushort_t* __restrict__ VB, const float* __restrict__ scale,
    const float* __restrict__ shift, const ushort_t* __restrict__ CTXB,
    float* __restrict__ out)
{
  float* qst = (float*)ldsc;                       // [256][33] f32 = 33792 B (also out_l)
  char* RbC = ldsc + 33792;                        // 2 x 9216 B  [64 dj][72]
  char* VbC = ldsc + 52224;                        // 2 x 5120 B  [64 v][40]
  ushort_t* Sl = (ushort_t*)(ldsc + 62464);        // 4 x [32][40] bf16 = 10240 B

  const int t = threadIdx.x;
  const int b = blockIdx.x >> 6;
  const int i1 = (blockIdx.x >> 1) & 31;
  const int half = blockIdx.x & 1;
  const int w = t >> 6, l = t & 63, ln = l & 31, hi = l >> 5;
  const int m = w & 3, nt = w >> 2;
  const int i2base = half * 16;

  const char* Rsrc0 = (const char*)RPEB;
  const char* Vsrc0 = (const char*)VB + (size_t)b * 32 * 5120;

  // issue async stage of slice i2 into buffer buf
  auto stage = [&](int i2, int buf) {
    const char* rs = Rsrc0 + (size_t)(i2 - i1 + 31) * 9216;
    const char* vs = Vsrc0 + (size_t)i2 * 5120;
    char* rd = RbC + buf * 9216;
    char* vd = VbC + buf * 5120;
    gl16(rs + w * 1024 + l * 16, rd + w * 1024 + l * 16);
    if (w == 0) gl16(rs + 8192 + l * 16, rd + 8192 + l * 16);
    else if (w <= 5) {
      const int gv = (w - 1) * 1024;
      gl16(vs + gv + l * 16, vd + gv + l * 16);
    }
  };

  stage(i2base, 0);  // prologue prefetch (async, overlaps q staging)

  // ---- stage scaled q [256 ch][32 j1] f32 ----
  {
    const int j1 = t & 31, c0 = (t >> 5) * 16;
    const float* src = P + (size_t)b * 1024 + i1 * 32 + j1;
#pragma unroll
    for (int i = 0; i < 16; ++i) {
      const int ch = c0 + i;
      qst[ch * 33 + j1] = src[(size_t)ch * 8192] * scale[ch] + shift[ch];
    }
  }
  __syncthreads();

  // ---- q A-fragments: row j1=ln, k = ks*16 + hi*8 + i ----
  short8 qf0, qf1, qf2, qf3;
  {
    S8 s;
#pragma unroll
    for (int i = 0; i < 8; ++i) s.u[i] = bfb(qst[(m * 64 + 0  + hi * 8 + i) * 33 + ln]);
    qf0 = s.v;
#pragma unroll
    for (int i = 0; i < 8; ++i) s.u[i] = bfb(qst[(m * 64 + 16 + hi * 8 + i) * 33 + ln]);
    qf1 = s.v;
#pragma unroll
    for (int i = 0; i < 8; ++i) s.u[i] = bfb(qst[(m * 64 + 32 + hi * 8 + i) * 33 + ln]);
    qf2 = s.v;
#pragma unroll
    for (int i = 0; i < 8; ++i) s.u[i] = bfb(qst[(m * 64 + 48 + hi * 8 + i) * 33 + ln]);
    qf3 = s.v;
  }

  f32x16 sv;
#pragma unroll
  for (int i = 0; i < 16; ++i) sv[i] = 0.f;

  for (int s = 0; s < 16; ++s) {
    const int cur = s & 1;
    if (s + 1 < 16) stage(i2base + s + 1, cur ^ 1);

    // T-GEMM: T[j1, dj] = sum_k q[k,j1] * rpe[di][dj][k]
    f32x16 tac;
#pragma unroll
    for (int i = 0; i < 16; ++i) tac[i] = 0.f;
    {
      const ushort_t* rb = (const ushort_t*)(RbC + cur * 9216) + (nt * 32 + ln) * 72 + hi * 8;
      tac = __builtin_amdgcn_mfma_f32_32x32x16_bf16(qf0, *(const short8*)(rb +  0), tac, 0, 0, 0);
      tac = __builtin_amdgcn_mfma_f32_32x32x16_bf16(qf1, *(const short8*)(rb + 16), tac, 0, 0, 0);
      tac = __builtin_amdgcn_mfma_f32_32x32x16_bf16(qf2, *(const short8*)(rb + 32), tac, 0, 0, 0);
      tac = __builtin_amdgcn_mfma_f32_32x32x16_bf16(qf3, *(const short8*)(rb + 48), tac, 0, 0, 0);
    }
    // shear: S[j1][j2 = dj + j1 - 31] = T[j1][dj]
    {
      ushort_t* sm = Sl + m * 1280;
      const int dj = nt * 32 + ln;
#pragma unroll
      for (int r = 0; r < 16; ++r) {
        const int j1 = (r & 3) + 8 * (r >> 2) + 4 * hi;
        const int j2 = dj + j1 - 31;
        if ((unsigned)j2 < 32u) sm[j1 * 40 + j2] = bfb(tac[r]);
      }
    }
    __syncthreads();  // Sl ready (also drains prefetch vmcnt)
    // SV: out[j1, v] += sum_j2 S[j1,j2] * V[v,j2]
    {
      const ushort_t* sa = Sl + m * 1280 + ln * 40 + hi * 8;
      const ushort_t* vb = (const ushort_t*)(VbC + cur * 5120) + (nt * 32 + ln) * 40 + hi * 8;
      sv = __builtin_amdgcn_mfma_f32_32x32x16_bf16(*(const short8*)(sa),      *(const short8*)(vb),      sv, 0, 0, 0);
      sv = __builtin_amdgcn_mfma_f32_32x32x16_bf16(*(const short8*)(sa + 16), *(const short8*)(vb + 16), sv, 0, 0, 0);
    }
    __syncthreads();  // protect Sl & buffers for next iter
  }

  // ---- content epilogue (half 0): out += q^T * ctx ----
  if (half == 0) {
    const char* cs = (const char*)CTXB + (size_t)b * 9216;
    gl16(cs + w * 1024 + l * 16, RbC + w * 1024 + l * 16);
    if (w == 0) gl16(cs + 8192 + l * 16, RbC + 8192 + l * 16);
    __syncthreads();
    const ushort_t* cb = (const ushort_t*)RbC + (nt * 32 + ln) * 72 + hi * 8;
    sv = __builtin_amdgcn_mfma_f32_32x32x16_bf16(qf0, *(const short8*)(cb +  0), sv, 0, 0, 0);
    sv = __builtin_amdgcn_mfma_f32_32x32x16_bf16(qf1, *(const short8*)(cb + 16), sv, 0, 0, 0);
    sv = __builtin_amdgcn_mfma_f32_32x32x16_bf16(qf2, *(const short8*)(cb + 32), sv, 0, 0, 0);
    sv = __builtin_amdgcn_mfma_f32_32x32x16_bf16(qf3, *(const short8*)(cb + 48), sv, 0, 0, 0);
  }

  // ---- stage to LDS then atomic add to out ----
  __syncthreads();
  float* out_l = qst;  // [256][33]
  {
    const int ch = m * 64 + nt * 32 + ln;
#pragma unroll
    for (int r = 0; r < 16; ++r) {
      const int j1 = (r & 3) + 8 * (r >> 2) + 4 * hi;
      out_l[ch * 33 + j1] = sv[r];
    }
  }
  __syncthreads();
  {
    const int ch = t >> 1, jh = (t & 1) * 16;
    float* dst = out + (size_t)b * 262144 + (size_t)ch * 1024 + i1 * 32 + jh;
    const float* srow = out_l + ch * 33 + jh;
#pragma unroll
    for (int g = 0; g < 16; ++g) atomicAdd(dst + g, srow[g]);
  }
}

// ---------------------------------------------------------------------------
extern "C" void kernel_launch(void* const* d_in, const int* in_sizes, int n_in,
                              void* d_out, int out_size, void* d_ws, size_t ws_size,
                              hipStream_t stream) {
  const float* x   = (const float*)d_in[0];
  const float* wq  = (const float*)d_in[1];
  const float* gq  = (const float*)d_in[2];
  const float* bq  = (const float*)d_in[3];
  const float* wk  = (const float*)d_in[4];
  const float* gk  = (const float*)d_in[5];
  const float* bk  = (const float*)d_in[6];
  const float* wv  = (const float*)d_in[7];
  const float* rpe = (const float*)d_in[8];
  float* out = (float*)d_out;
  char* W = (char*)d_ws;

  float* P        = (float*)W;                       // 12,582,912 B
  float* KS       = (float*)(W + 12582912);          //  2,097,152
  float* SCALE    = (float*)(W + 14680064);          //      1,280
  float* SHIFT    = (float*)(W + 14681344);          //      1,280
  float* CTXP     = (float*)(W + 14682624);          //  2,097,152
  ushort_t* CTXB  = (ushort_t*)(W + 16779776);       //     73,728
  ushort_t* RPEB  = (ushort_t*)(W + 16853504);       //    580,608
  ushort_t* VB    = (ushort_t*)(W + 17434112);       //  1,310,720
  ushort_t* WB    = (ushort_t*)(W + 18744832);       //    196,608
  ushort_t* XBT   = (ushort_t*)(W + 18941440);       //  4,194,304

  hipMemsetAsync(out, 0, (size_t)out_size * sizeof(float), stream);

  k_prep<<<1135, 256, 0, stream>>>(rpe, wq, wk, wv, x, RPEB, WB, XBT);
  k_projm<<<dim3(6, 64), 256, 0, stream>>>(WB, XBT, P, VB);
  k_stats<<<320, 256, 0, stream>>>(P, gq, bq, gk, bk, SCALE, SHIFT);
  k_softmax<<<512, 256, 0, stream>>>(P, SCALE, SHIFT, KS);
  k_ctx<<<dim3(8, 16), 256, 0, stream>>>(KS, P, CTXP);
  k_ctxred<<<128, 256, 0, stream>>>(CTXP, CTXB);

  hipFuncSetAttribute((const void*)k_pos,
                      hipFuncAttributeMaxDynamicSharedMemorySize, 72704);
  k_pos<<<512, 512, 72704, stream>>>(P, RPEB, VB, SCALE, SHIFT, CTXB, out);
}

// Round 4
// 64.685 us; speedup vs baseline: 3.9831x; 3.9831x over previous
//
#include <hip/hip_runtime.h>

// SelfAttention (lambda attention) on MI355X.
// B=8, C=256, H=W=32, n=1024, DK=64, HEADS=4, DQ=256, DV=64. SF = 64^-0.25
#define SFC 0.35355339059327373f

typedef __attribute__((ext_vector_type(8))) short short8;
typedef __attribute__((ext_vector_type(16))) float f32x16;
typedef unsigned short ushort_t;

__device__ __forceinline__ float4 ld4(const float* p) { return *reinterpret_cast<const float4*>(p); }
__device__ __forceinline__ void st4(float* p, float4 v) { *reinterpret_cast<float4*>(p) = v; }

union F4 { float4 v; float f[4]; };
union S8 { short8 v; ushort_t u[8]; };

__device__ __forceinline__ ushort_t bfb(float f) {
  union { float f; unsigned u; } a; a.f = f;
  unsigned r = a.u + 0x7FFFu + ((a.u >> 16) & 1u);   // RNE f32->bf16
  return (ushort_t)(r >> 16);
}

__device__ __forceinline__ void gl16(const void* g, void* l) {
  __builtin_amdgcn_global_load_lds(
      (const __attribute__((address_space(1))) unsigned int*)g,
      (__attribute__((address_space(3))) unsigned int*)l, 16, 0, 0);
}

// ---------------------------------------------------------------------------
// K0: prep. blocks 0..62: rpe -> RPEB bf16 [di][64 dj][72] (9216B slices)
//           blocks 63..110: Wq/Wk/Wv -> WB bf16 [384][256]
//           blocks 111..1134: x -> XBT bf16 [b*1024+n][256 c]
// ---------------------------------------------------------------------------
__global__ __launch_bounds__(256) void k_prep(
    const float* __restrict__ rpe, const float* __restrict__ wq,
    const float* __restrict__ wk, const float* __restrict__ wv,
    const float* __restrict__ x, ushort_t* __restrict__ RPEB,
    ushort_t* __restrict__ WB, ushort_t* __restrict__ XBT)
{
  const int bx = blockIdx.x, t = threadIdx.x;
  if (bx < 63) {
    const int di = bx;
#pragma unroll
    for (int i = 0; i < 2; ++i) {
      const int c = t + i * 256;
      if (c < 504) {
        const int dj = c >> 3, k8 = (c & 7) * 8;
        const float* s = rpe + (size_t)di * 4032 + dj * 64 + k8;
        float4 a = ld4(s), b = ld4(s + 4);
        S8 o;
        o.u[0] = bfb(a.x); o.u[1] = bfb(a.y); o.u[2] = bfb(a.z); o.u[3] = bfb(a.w);
        o.u[4] = bfb(b.x); o.u[5] = bfb(b.y); o.u[6] = bfb(b.z); o.u[7] = bfb(b.w);
        *(short8*)(RPEB + (size_t)di * 4608 + dj * 72 + k8) = o.v;
      }
    }
  } else if (bx < 111) {
    const int cc = (bx - 63) * 256 + t;        // 0..12287
    const int o = cc >> 5, k8 = (cc & 31) * 8;
    const float* src = (o < 256) ? (wq + o * 256)
                      : (o < 320) ? (wk + (o - 256) * 256)
                                  : (wv + (o - 320) * 256);
    float4 a = ld4(src + k8), b = ld4(src + k8 + 4);
    S8 s;
    s.u[0] = bfb(a.x); s.u[1] = bfb(a.y); s.u[2] = bfb(a.z); s.u[3] = bfb(a.w);
    s.u[4] = bfb(b.x); s.u[5] = bfb(b.y); s.u[6] = bfb(b.z); s.u[7] = bfb(b.w);
    *(short8*)(WB + (size_t)o * 256 + k8) = s.v;
  } else {
    const int id = (bx - 111) * 256 + t;       // 0..262143
    const int ng = id & 8191, c8 = id >> 13;   // n global, c chunk
    const int bb = ng >> 10, nn = ng & 1023;
    const float* src = x + (size_t)bb * 262144 + (size_t)(c8 * 8) * 1024 + nn;
    S8 s;
#pragma unroll
    for (int j = 0; j < 8; ++j) s.u[j] = bfb(src[(size_t)j * 1024]);
    *(short8*)(XBT + (size_t)ng * 256 + c8 * 8) = s.v;
  }
}

// ---------------------------------------------------------------------------
// K1: projection GEMM via MFMA: P[o][col] = sum_c WB[o][c] * XBT[col][c].
// Blocks with bm==5 (V rows) also emit VB bf16 slices [b][i2][v][40].
// ---------------------------------------------------------------------------
__global__ __launch_bounds__(256) void k_projm(
    const ushort_t* __restrict__ WB, const ushort_t* __restrict__ XBT,
    float* __restrict__ P, ushort_t* __restrict__ VB)
{
  __shared__ ushort_t At[64 * 72];
  __shared__ ushort_t Bt[128 * 72];
  const int t = threadIdx.x;
  const int bm = blockIdx.x, bn = blockIdx.y;
  const int o0 = bm * 64, col0 = bn * 128;
  const int w = t >> 6, l = t & 63, ln = l & 31, hi = l >> 5;
  const int wm = w & 1, wn = w >> 1;

  f32x16 acc0, acc1;
#pragma unroll
  for (int i = 0; i < 16; ++i) { acc0[i] = 0.f; acc1[i] = 0.f; }

  for (int k0 = 0; k0 < 256; k0 += 64) {
    __syncthreads();
#pragma unroll
    for (int i = 0; i < 2; ++i) {
      const int c = t + i * 256, row = c >> 3, k8 = (c & 7) * 8;
      *(short8*)(At + row * 72 + k8) =
          *(const short8*)(WB + (size_t)(o0 + row) * 256 + k0 + k8);
    }
#pragma unroll
    for (int i = 0; i < 4; ++i) {
      const int c = t + i * 256, row = c >> 3, k8 = (c & 7) * 8;
      *(short8*)(Bt + row * 72 + k8) =
          *(const short8*)(XBT + (size_t)(col0 + row) * 256 + k0 + k8);
    }
    __syncthreads();
    const ushort_t* ka  = At + (wm * 32 + ln) * 72 + hi * 8;
    const ushort_t* kb0 = Bt + (wn * 64 + ln) * 72 + hi * 8;
    const ushort_t* kb1 = Bt + (wn * 64 + 32 + ln) * 72 + hi * 8;
#pragma unroll
    for (int kc = 0; kc < 4; ++kc) {
      short8 a = *(const short8*)(ka + kc * 16);
      acc0 = __builtin_amdgcn_mfma_f32_32x32x16_bf16(a, *(const short8*)(kb0 + kc * 16), acc0, 0, 0, 0);
      acc1 = __builtin_amdgcn_mfma_f32_32x32x16_bf16(a, *(const short8*)(kb1 + kc * 16), acc1, 0, 0, 0);
    }
  }

#pragma unroll
  for (int r = 0; r < 16; ++r) {
    const int o = o0 + wm * 32 + (r & 3) + 8 * (r >> 2) + 4 * hi;
    float* dst = P + (size_t)o * 8192 + col0 + wn * 64 + ln;
    dst[0]  = acc0[r];
    dst[32] = acc1[r];
  }
  if (bm == 5) {
    const int b2 = bn >> 3;
#pragma unroll
    for (int r = 0; r < 16; ++r) {
      const int v = wm * 32 + (r & 3) + 8 * (r >> 2) + 4 * hi;
      const int i20 = (bn & 7) * 4 + wn * 2;
      VB[(size_t)(b2 * 32 + i20) * 2560 + v * 40 + ln]     = bfb(acc0[r]);
      VB[(size_t)(b2 * 32 + i20 + 1) * 2560 + v * 40 + ln] = bfb(acc1[r]);
    }
  }
}

// ---------------------------------------------------------------------------
// K2: BN stats per channel, folded with gamma/beta and SF.
// ---------------------------------------------------------------------------
__global__ __launch_bounds__(256) void k_stats(
    const float* __restrict__ P, const float* __restrict__ gq,
    const float* __restrict__ bq, const float* __restrict__ gk,
    const float* __restrict__ bk, float* __restrict__ scale,
    float* __restrict__ shift)
{
  const int ch = blockIdx.x;  // 0..319
  const float4* row = (const float4*)(P + (size_t)ch * 8192);
  float s = 0.f, ss = 0.f;
  for (int i = threadIdx.x; i < 2048; i += 256) {
    float4 v = row[i];
    s  += v.x + v.y + v.z + v.w;
    ss += v.x * v.x + v.y * v.y + v.z * v.z + v.w * v.w;
  }
#pragma unroll
  for (int off = 32; off; off >>= 1) {
    s  += __shfl_down(s, off, 64);
    ss += __shfl_down(ss, off, 64);
  }
  __shared__ float red[8];
  const int w = threadIdx.x >> 6, lane = threadIdx.x & 63;
  if (lane == 0) { red[w] = s; red[4 + w] = ss; }
  __syncthreads();
  if (threadIdx.x == 0) {
    s = red[0] + red[1] + red[2] + red[3];
    ss = red[4] + red[5] + red[6] + red[7];
    const float mu = s * (1.0f / 8192.0f);
    const float var = ss * (1.0f / 8192.0f) - mu * mu;
    const float rsig = rsqrtf(var + 1e-5f);
    float g, be;
    if (ch < 256) { g = gq[ch]; be = bq[ch]; }
    else          { g = gk[ch - 256]; be = bk[ch - 256]; }
    const float sc = rsig * g * SFC;
    scale[ch] = sc;
    shift[ch] = be * SFC - mu * sc;
  }
}

// ---------------------------------------------------------------------------
// K3: softmax over n for each (b, k-channel).
// ---------------------------------------------------------------------------
__global__ __launch_bounds__(256) void k_softmax(
    const float* __restrict__ P, const float* __restrict__ scale,
    const float* __restrict__ shift, float* __restrict__ KS)
{
  const int b = blockIdx.x >> 6, kc = blockIdx.x & 63;
  const int ch = 256 + kc;
  const float4* row = (const float4*)(P + (size_t)ch * 8192 + b * 1024);
  const float sc = scale[ch], sh = shift[ch];
  float4 v = row[threadIdx.x];
  float y0 = v.x * sc + sh, y1 = v.y * sc + sh;
  float y2 = v.z * sc + sh, y3 = v.w * sc + sh;
  float m = fmaxf(fmaxf(y0, y1), fmaxf(y2, y3));
#pragma unroll
  for (int off = 32; off; off >>= 1) m = fmaxf(m, __shfl_xor(m, off, 64));
  __shared__ float red[8];
  const int w = threadIdx.x >> 6, lane = threadIdx.x & 63;
  if (lane == 0) red[w] = m;
  __syncthreads();
  m = fmaxf(fmaxf(red[0], red[1]), fmaxf(red[2], red[3]));
  const float e0 = __expf(y0 - m), e1 = __expf(y1 - m);
  const float e2 = __expf(y2 - m), e3 = __expf(y3 - m);
  float su = e0 + e1 + e2 + e3;
#pragma unroll
  for (int off = 32; off; off >>= 1) su += __shfl_xor(su, off, 64);
  if (lane == 0) red[4 + w] = su;
  __syncthreads();
  const float inv = 1.0f / (red[4] + red[5] + red[6] + red[7]);
  ((float4*)(KS + (size_t)(b * 64 + kc) * 1024))[threadIdx.x] =
      make_float4(e0 * inv, e1 * inv, e2 * inv, e3 * inv);
}

// ---------------------------------------------------------------------------
// K4: content context partials: ctxp[b][nc][kc][vc] = sum_{n in chunk} ks*v
// ---------------------------------------------------------------------------
__global__ __launch_bounds__(256) void k_ctx(
    const float* __restrict__ KS, const float* __restrict__ P,
    float* __restrict__ ctxp)
{
  __shared__ float ksl[64][64];
  __shared__ float vl[64][64];
  const int t = threadIdx.x;
  const int b = blockIdx.x;
  const int n0 = blockIdx.y * 64;
  {
    const int c = t >> 2, q4 = (t & 3) * 16;
    const float* s = KS + (size_t)(b * 64 + c) * 1024 + n0 + q4;
#pragma unroll
    for (int i = 0; i < 16; ++i) ksl[q4 + i][c] = s[i];
    const float* v = P + (size_t)(320 + c) * 8192 + b * 1024 + n0 + q4;
#pragma unroll
    for (int i = 0; i < 16; ++i) vl[q4 + i][c] = v[i];
  }
  __syncthreads();
  const int tr = t >> 4, tc = t & 15;
  float acc[4][4] = {};
#pragma unroll 4
  for (int nn = 0; nn < 64; ++nn) {
    F4 a; a.v = ld4(&ksl[nn][tr * 4]);
    F4 bv; bv.v = ld4(&vl[nn][tc * 4]);
#pragma unroll
    for (int i = 0; i < 4; ++i)
#pragma unroll
      for (int j = 0; j < 4; ++j) acc[i][j] += a.f[i] * bv.f[j];
  }
  float* dst = ctxp + (size_t)(b * 16 + blockIdx.y) * 4096;
#pragma unroll
  for (int i = 0; i < 4; ++i)
    st4(dst + (tr * 4 + i) * 64 + tc * 4,
        make_float4(acc[i][0], acc[i][1], acc[i][2], acc[i][3]));
}

// reduce partials -> CTXB bf16 [b][v=64][72 k-pad] (9216B per b)
__global__ __launch_bounds__(256) void k_ctxred(
    const float* __restrict__ ctxp, ushort_t* __restrict__ ctxb)
{
  const int i = blockIdx.x * 256 + threadIdx.x;  // 32768
  const int b = i >> 12, r = i & 4095, kc = r >> 6, vc = r & 63;
  float s = 0.f;
#pragma unroll
  for (int c = 0; c < 16; ++c) s += ctxp[(size_t)(b * 16 + c) * 4096 + r];
  ctxb[(size_t)b * 4608 + vc * 72 + kc] = bfb(s);
}

// ---------------------------------------------------------------------------
// K5: positional lambda, block = (b, i1), grid 256, 8 waves.
// Wave w: head m = w&3, i2-group g = w>>2 (i2 in [g*16, g*16+16)).
// Each wave owns a FULL head per i2: 8 T-MFMAs (dj 0..63), private-LDS shear
// (within-wave, no barrier), 4 SV-MFMAs. One barrier per iteration (staging
// double-buffer flip via global_load_lds). Groups' partials combined in LDS;
// single coalesced store. No atomics.
// ---------------------------------------------------------------------------
extern __shared__ char ldsc[];

__global__ __launch_bounds__(512) void k_pos(
    const float* __restrict__ P, const ushort_t* __restrict__ RPEB,
    const ushort_t* __restrict__ VB, const float* __restrict__ scale,
    const float* __restrict__ shift, const ushort_t* __restrict__ CTXB,
    float* __restrict__ out)
{
  float* qst = (float*)ldsc;                 // [256][33] f32 = 33792 B (later out_l)
  char* RbC = ldsc + 33792;                  // [g][buf] 9216 B each = 36864 B
  char* VbC = ldsc + 70656;                  // [g][buf] 5120 B each = 20480 B
  ushort_t* SlB = (ushort_t*)(ldsc + 91136); // 8 waves x 1280 ushorts = 20480 B
                                             // total 111616 B

  const int t = threadIdx.x;
  const int b = blockIdx.x >> 5, i1 = blockIdx.x & 31;
  const int w = t >> 6, l = t & 63, ln = l & 31, hi = l >> 5;
  const int m = w & 3, g = w >> 2;           // head, i2-group; wave-in-group = m

  // stage slice i2 for group g into buffer buf (async, wave-split)
  auto stage = [&](int i2, int buf) {
    const char* rs = (const char*)RPEB + (size_t)(i2 - i1 + 31) * 9216;
    const char* vs = (const char*)VB + (size_t)(b * 32 + i2) * 5120;
    char* rd = RbC + g * 18432 + buf * 9216;
    char* vd = VbC + g * 10240 + buf * 5120;
#pragma unroll
    for (int j = 0; j < 4; ++j) {
      const int chunk = m * 4 + j;           // 0..15 within group
      const int off = chunk * 1024 + l * 16;
      if (chunk < 9)       gl16(rs + off, rd + off);
      else if (chunk < 14) gl16(vs + off - 9216, vd + off - 9216);
    }
  };

  const int i2base = g * 16;
  stage(i2base, 0);   // prologue prefetch (overlaps q staging)

  // ---- stage scaled q [256 ch][32 j1] f32 ----
  {
    const int j1 = t & 31, c0 = (t >> 5) * 16;
    const float* src = P + (size_t)b * 1024 + i1 * 32 + j1;
#pragma unroll
    for (int i = 0; i < 16; ++i) {
      const int ch = c0 + i;
      qst[ch * 33 + j1] = src[(size_t)ch * 8192] * scale[ch] + shift[ch];
    }
  }
  __syncthreads();

  // ---- q A-fragments for head m: row j1=ln, k = kc*16 + hi*8 + i ----
  short8 qf[4];
#pragma unroll
  for (int kc = 0; kc < 4; ++kc) {
    S8 s;
#pragma unroll
    for (int i = 0; i < 8; ++i)
      s.u[i] = bfb(qst[(m * 64 + kc * 16 + hi * 8 + i) * 33 + ln]);
    qf[kc] = s.v;
  }

  f32x16 sv0, sv1;
#pragma unroll
  for (int i = 0; i < 16; ++i) { sv0[i] = 0.f; sv1[i] = 0.f; }

  ushort_t* sm = SlB + w * 1280;             // private S tile [32 j1][40]

  for (int s = 0; s < 16; ++s) {
    const int cur = s & 1;
    if (s + 1 < 16) stage(i2base + s + 1, cur ^ 1);

    // T-GEMM: T[j1, dj] = sum_k q[k,j1]*rpe[di][dj][k], both dj-tiles
    f32x16 t0, t1;
#pragma unroll
    for (int i = 0; i < 16; ++i) { t0[i] = 0.f; t1[i] = 0.f; }
    {
      const ushort_t* rb = (const ushort_t*)(RbC + g * 18432 + cur * 9216);
      const ushort_t* r0 = rb + ln * 72 + hi * 8;
      const ushort_t* r1 = rb + (32 + ln) * 72 + hi * 8;
#pragma unroll
      for (int kc = 0; kc < 4; ++kc) {
        t0 = __builtin_amdgcn_mfma_f32_32x32x16_bf16(qf[kc], *(const short8*)(r0 + kc * 16), t0, 0, 0, 0);
        t1 = __builtin_amdgcn_mfma_f32_32x32x16_bf16(qf[kc], *(const short8*)(r1 + kc * 16), t1, 0, 0, 0);
      }
    }
    // shear into private Sl: S[j1][j2 = dj + j1 - 31] (within-wave only)
#pragma unroll
    for (int r = 0; r < 16; ++r) {
      const int j1 = (r & 3) + 8 * (r >> 2) + 4 * hi;
      const int j2a = ln + j1 - 31;          // dj = ln
      const int j2b = 32 + ln + j1 - 31;     // dj = 32+ln
      if ((unsigned)j2a < 32u) sm[j1 * 40 + j2a] = bfb(t0[r]);
      if ((unsigned)j2b < 32u) sm[j1 * 40 + j2b] = bfb(t1[r]);
    }
    // SV: out[j1, v] += sum_j2 S[j1,j2] * V[v,j2]  (reads own Sl; lgkmcnt only)
    {
      const ushort_t* sa = sm + ln * 40 + hi * 8;
      const ushort_t* vbp = (const ushort_t*)(VbC + g * 10240 + cur * 5120);
      const ushort_t* v0 = vbp + ln * 40 + hi * 8;
      const ushort_t* v1 = vbp + (32 + ln) * 40 + hi * 8;
      short8 sA0 = *(const short8*)(sa);
      short8 sA1 = *(const short8*)(sa + 16);
      sv0 = __builtin_amdgcn_mfma_f32_32x32x16_bf16(sA0, *(const short8*)(v0),      sv0, 0, 0, 0);
      sv0 = __builtin_amdgcn_mfma_f32_32x32x16_bf16(sA1, *(const short8*)(v0 + 16), sv0, 0, 0, 0);
      sv1 = __builtin_amdgcn_mfma_f32_32x32x16_bf16(sA0, *(const short8*)(v1),      sv1, 0, 0, 0);
      sv1 = __builtin_amdgcn_mfma_f32_32x32x16_bf16(sA1, *(const short8*)(v1 + 16), sv1, 0, 0, 0);
    }
    __syncthreads();   // buffer flip: next slice staged & visible
  }

  // ---- content epilogue: stage CTXB (all waves), group 0 adds GEMM ----
  {
    const char* cs = (const char*)CTXB + (size_t)b * 9216;
    gl16(cs + w * 1024 + l * 16, RbC + w * 1024 + l * 16);
    if (w == 0) gl16(cs + 8192 + l * 16, RbC + 8192 + l * 16);
  }
  __syncthreads();     // drains staging; RbC = ctx^T [v][72]

  float* out_l = qst;  // [256][33]
  if (g == 0) {
    const ushort_t* cb = (const ushort_t*)RbC;
    const ushort_t* c0 = cb + ln * 72 + hi * 8;
    const ushort_t* c1 = cb + (32 + ln) * 72 + hi * 8;
#pragma unroll
    for (int kc = 0; kc < 4; ++kc) {
      sv0 = __builtin_amdgcn_mfma_f32_32x32x16_bf16(qf[kc], *(const short8*)(c0 + kc * 16), sv0, 0, 0, 0);
      sv1 = __builtin_amdgcn_mfma_f32_32x32x16_bf16(qf[kc], *(const short8*)(c1 + kc * 16), sv1, 0, 0, 0);
    }
  } else {
    // group 1 writes its partials
#pragma unroll
    for (int r = 0; r < 16; ++r) {
      const int j1 = (r & 3) + 8 * (r >> 2) + 4 * hi;
      out_l[(m * 64 + ln) * 33 + j1]      = sv0[r];
      out_l[(m * 64 + 32 + ln) * 33 + j1] = sv1[r];
    }
  }
  __syncthreads();
  if (g == 0) {
#pragma unroll
    for (int r = 0; r < 16; ++r) {
      const int j1 = (r & 3) + 8 * (r >> 2) + 4 * hi;
      out_l[(m * 64 + ln) * 33 + j1]      += sv0[r];
      out_l[(m * 64 + 32 + ln) * 33 + j1] += sv1[r];
    }
  }
  __syncthreads();
  // ---- coalesced store ----
  {
    const int ch = t >> 1, jh = (t & 1) * 16;
    float* dst = out + (size_t)b * 262144 + (size_t)ch * 1024 + i1 * 32 + jh;
    const float* srow = out_l + ch * 33 + jh;
#pragma unroll
    for (int gq2 = 0; gq2 < 4; ++gq2)
      st4(dst + gq2 * 4, make_float4(srow[gq2 * 4], srow[gq2 * 4 + 1],
                                     srow[gq2 * 4 + 2], srow[gq2 * 4 + 3]));
  }
}

// ---------------------------------------------------------------------------
extern "C" void kernel_launch(void* const* d_in, const int* in_sizes, int n_in,
                              void* d_out, int out_size, void* d_ws, size_t ws_size,
                              hipStream_t stream) {
  const float* x   = (const float*)d_in[0];
  const float* wq  = (const float*)d_in[1];
  const float* gq  = (const float*)d_in[2];
  const float* bq  = (const float*)d_in[3];
  const float* wk  = (const float*)d_in[4];
  const float* gk  = (const float*)d_in[5];
  const float* bk  = (const float*)d_in[6];
  const float* wv  = (const float*)d_in[7];
  const float* rpe = (const float*)d_in[8];
  float* out = (float*)d_out;
  char* W = (char*)d_ws;

  float* P        = (float*)W;                       // 12,582,912 B
  float* KS       = (float*)(W + 12582912);          //  2,097,152
  float* SCALE    = (float*)(W + 14680064);          //      1,280
  float* SHIFT    = (float*)(W + 14681344);          //      1,280
  float* CTXP     = (float*)(W + 14682624);          //  2,097,152
  ushort_t* CTXB  = (ushort_t*)(W + 16779776);       //     73,728
  ushort_t* RPEB  = (ushort_t*)(W + 16853504);       //    580,608
  ushort_t* VB    = (ushort_t*)(W + 17434112);       //  1,310,720
  ushort_t* WB    = (ushort_t*)(W + 18744832);       //    196,608
  ushort_t* XBT   = (ushort_t*)(W + 18941440);       //  4,194,304

  k_prep<<<1135, 256, 0, stream>>>(rpe, wq, wk, wv, x, RPEB, WB, XBT);
  k_projm<<<dim3(6, 64), 256, 0, stream>>>(WB, XBT, P, VB);
  k_stats<<<320, 256, 0, stream>>>(P, gq, bq, gk, bk, SCALE, SHIFT);
  k_softmax<<<512, 256, 0, stream>>>(P, SCALE, SHIFT, KS);
  k_ctx<<<dim3(8, 16), 256, 0, stream>>>(KS, P, CTXP);
  k_ctxred<<<128, 256, 0, stream>>>(CTXP, CTXB);

  hipFuncSetAttribute((const void*)k_pos,
                      hipFuncAttributeMaxDynamicSharedMemorySize, 111616);
  k_pos<<<256, 512, 111616, stream>>>(P, RPEB, VB, SCALE, SHIFT, CTXB, out);
}